// Round 1
// baseline (505.969 us; speedup 1.0000x reference)
//
#include <hip/hip_runtime.h>
#include <stdint.h>

#define NN 8192
#define FEAT 16

// conv_feats[i] = sigmoid(x[i,:] . w + b)   (fp32 in, fp32 out to ws)
__global__ void conv_kernel(const float* __restrict__ x,
                            const float* __restrict__ w,
                            const float* __restrict__ b,
                            float* __restrict__ out) {
    int i = blockIdx.x * blockDim.x + threadIdx.x;
    if (i >= NN) return;
    const float4* xr = (const float4*)(x + (size_t)i * FEAT);
    const float4* wr = (const float4*)w;
    float acc = b[0];
#pragma unroll
    for (int k = 0; k < 4; ++k) {
        float4 a = xr[k], ww = wr[k];
        acc += a.x * ww.x + a.y * ww.y + a.z * ww.z + a.w * ww.w;
    }
    out[i] = 1.f / (1.f + __expf(-acc));
}

// y[row] = act( W[row,:] . x + bias[row] )
// One row per WAVE (64 lanes): no LDS, no __syncthreads, pure streaming +
// in-wave shuffle reduce. Grid 2048 blocks x 256 thr = 8192 waves = 8192 rows,
// exactly 8 blocks/CU -> single dispatch round.
template <bool TANH>
__global__ __launch_bounds__(256)
void matvec_wave(const float* __restrict__ W,
                 const float* __restrict__ x,
                 const float* __restrict__ bias,
                 float* __restrict__ y) {
    const int wave = threadIdx.x >> 6;
    const int lane = threadIdx.x & 63;
    const int row  = (blockIdx.x << 2) + wave;
    const float* wr = W + (size_t)row * NN;

    // 8192 floats/row = 2048 float4 = 32 float4 per lane
    float acc0 = 0.f, acc1 = 0.f;
#pragma unroll 4
    for (int it = 0; it < 32; it += 2) {
        const int b0 = ((it + 0) * 64 + lane) * 4;
        const int b1 = ((it + 1) * 64 + lane) * 4;
        float4 w0 = *(const float4*)(wr + b0);
        float4 x0 = *(const float4*)(x  + b0);
        float4 w1 = *(const float4*)(wr + b1);
        float4 x1 = *(const float4*)(x  + b1);
        acc0 += w0.x * x0.x + w0.y * x0.y + w0.z * x0.z + w0.w * x0.w;
        acc1 += w1.x * x1.x + w1.y * x1.y + w1.z * x1.z + w1.w * x1.w;
    }
    float acc = acc0 + acc1;

#pragma unroll
    for (int off = 32; off > 0; off >>= 1)
        acc += __shfl_down(acc, off, 64);

    if (lane == 0) {
        float r = acc + bias[row];
        if (TANH) r = tanhf(r);
        y[row] = r;
    }
}

extern "C" void kernel_launch(void* const* d_in, const int* in_sizes, int n_in,
                              void* d_out, int out_size, void* d_ws, size_t ws_size,
                              hipStream_t stream) {
    const float* x      = (const float*)d_in[0]; // (8192,16)
    const float* conv_w = (const float*)d_in[1]; // (16,)
    const float* conv_b = (const float*)d_in[2]; // (1,)
    const float* W1     = (const float*)d_in[3]; // (8192,8192)
    const float* b1     = (const float*)d_in[4]; // (8192,)
    const float* W2     = (const float*)d_in[5]; // (8192,8192)
    const float* b2     = (const float*)d_in[6]; // (8192,)
    float* out = (float*)d_out;                  // (8192,) fp32

    float* conv_feats = (float*)d_ws;            // 8192 floats
    float* h          = conv_feats + NN;         // 8192 floats

    conv_kernel<<<NN / 256, 256, 0, stream>>>(x, conv_w, conv_b, conv_feats);
    matvec_wave<true ><<<NN / 4, 256, 0, stream>>>(W1, conv_feats, b1, h);
    matvec_wave<false><<<NN / 4, 256, 0, stream>>>(W2, h, b2, out);
}